// Round 11
// baseline (50.160 us; speedup 1.0000x reference)
//
#include <hip/hip_runtime.h>
#include <hip/hip_bf16.h>
#include <math.h>

#define Bq 8
#define Nq 1024
#define Dq 256
#define Hq 8
#define HDq 32
#define LOG2E 1.44269504f

typedef __attribute__((ext_vector_type(8)))  short short8v;
typedef __attribute__((ext_vector_type(4)))  float f32x4;
typedef __attribute__((ext_vector_type(16))) float f32x16;

__device__ __forceinline__ void gload_lds16(const void* g, void* l) {
    __builtin_amdgcn_global_load_lds(
        (const __attribute__((address_space(1))) void*)g,
        (__attribute__((address_space(3))) void*)l, 16, 0, 0);
}

// ---------------------------------------------------------------------------
// Kernel 1 (fused role-split):
//  blocks [0,512):   bf16 MFMA GEMM h = x*W^T + b, epilogue -> h_bT (bf16,
//                    transposed) + s_i2/s_j2 (prescaled by LOG2E)
//  blocks [512,2560): pack adj rows into bitmasks adjw[b][i][0:32)
// ---------------------------------------------------------------------------
__global__ __launch_bounds__(256) void gemm_pack(const float* __restrict__ x,
                                                 const float* __restrict__ W,
                                                 const float* __restrict__ Wb,
                                                 const float* __restrict__ a,
                                                 const int* __restrict__ adj,
                                                 __hip_bfloat16* __restrict__ h_bT,
                                                 float* __restrict__ s_i2,
                                                 float* __restrict__ s_j2,
                                                 unsigned* __restrict__ adjw) {
    __shared__ __hip_bfloat16 xs[64][68];
    __shared__ __hip_bfloat16 wsm[64][68];
    __shared__ __hip_bfloat16 ht[64][72];
    const int t = threadIdx.x;
    const int lane = t & 63, wv = t >> 6;

    if (blockIdx.x >= 512) {
        const size_t row = ((size_t)blockIdx.x - 512) * 4 + wv;   // 0..8191
        const int* ar = adj + row * Nq;
        unsigned* wr = adjw + row * 32;
        #pragma unroll
        for (int it = 0; it < 16; ++it) {
            int v = ar[it * 64 + lane];
            unsigned long long mask = __ballot(v != 0);
            if (lane == 0) {
                wr[it * 2 + 0] = (unsigned)mask;
                wr[it * 2 + 1] = (unsigned)(mask >> 32);
            }
        }
        return;
    }

    const int m0 = (blockIdx.x & 127) * 64;
    const int o0 = (blockIdx.x >> 7) * 64;
    const int lo = lane & 31, hi = lane >> 5;
    const int mw = (wv & 1) * 32, ow = (wv >> 1) * 32;
    const int b = m0 >> 10;
    f32x16 acc = 0.f;

    for (int k0 = 0; k0 < 256; k0 += 64) {
        __syncthreads();
        #pragma unroll
        for (int it = 0; it < 4; ++it) {
            int f4  = t + it * 256;
            int row = f4 >> 4;
            int c4  = (f4 & 15) * 4;
            float4 xv = *(const float4*)(x + (size_t)(m0 + row) * 256 + k0 + c4);
            float4 wv2 = *(const float4*)(W + (size_t)(o0 + row) * 256 + k0 + c4);
            union { ushort4 u; __bf16 e[4]; } xb, wb;
            xb.e[0] = (__bf16)xv.x; xb.e[1] = (__bf16)xv.y;
            xb.e[2] = (__bf16)xv.z; xb.e[3] = (__bf16)xv.w;
            wb.e[0] = (__bf16)wv2.x; wb.e[1] = (__bf16)wv2.y;
            wb.e[2] = (__bf16)wv2.z; wb.e[3] = (__bf16)wv2.w;
            *(ushort4*)(&xs[row][c4])  = xb.u;
            *(ushort4*)(&wsm[row][c4]) = wb.u;
        }
        __syncthreads();
        #pragma unroll
        for (int kk = 0; kk < 4; ++kk) {
            short8v av = *(const short8v*)(&xs[mw + lo][kk * 16 + hi * 8]);
            short8v bv = *(const short8v*)(&wsm[ow + lo][kk * 16 + hi * 8]);
            acc = __builtin_amdgcn_mfma_f32_32x32x16_bf16(av, bv, acc, 0, 0, 0);
        }
    }

    __syncthreads();
    const float bias = Wb[o0 + ow + lo];
    #pragma unroll
    for (int rg = 0; rg < 16; ++rg) {
        int row = (rg & 3) + 8 * (rg >> 2) + 4 * hi;
        float v = acc[rg] + bias;
        ht[ow + lo][mw + row] = (__hip_bfloat16)v;
    }
    __syncthreads();

    #pragma unroll
    for (int it = 0; it < 2; ++it) {
        int s8 = t + it * 256;
        int ol = s8 >> 3;
        int n8 = (s8 & 7) * 8;
        short8v v = *(const short8v*)(&ht[ol][n8]);
        int o = o0 + ol;
        size_t drow = (size_t)((b * Hq + (o >> 5)) * HDq + (o & 31));
        *(short8v*)((unsigned short*)h_bT + drow * Nq + (m0 & 1023) + n8) = v;
    }
    // s projections: 256 threads, each one 32-dot.
    {
        int which = t >> 7;
        int hd = (t >> 6) & 1, nl = t & 63;
        const float* ab = a + b * 64 + which * 32;
        float s = 0.f;
        #pragma unroll
        for (int d = 0; d < 32; ++d)
            s += (float)ht[hd * 32 + d][nl] * ab[d];
        int bh = b * Hq + (o0 >> 5) + hd;
        int n  = (m0 & 1023) + nl;
        (which ? s_j2 : s_i2)[(size_t)bh * Nq + n] = s * LOG2E;
    }
}

// ---------------------------------------------------------------------------
// Kernel 2: attention v10 — B-read amortization via M-tiling:
// block = 64 i-rows of one bh; wave wv owns j-QUARTER (64 j of each 256-j
// chunk) and computes partial PV for ALL 64 i (4 i-tiles of 16). Every
// B-fragment ds_read is reused by 4 i-tiles -> LDS read traffic /4.
// Staging: v9's counted-vmcnt dbuf (batch = 4 h-gload + 1 sjs-gload + 4
// mask uint2 = 9 VMEM/wave; steady-state vmcnt(9), never 0 until drain).
// End: cross-wave combine of j-quarter partials via 36KB LDS overlay
// (reuses staging buffer; stride-69 pad), normalized bf16 att out.
// ---------------------------------------------------------------------------
__global__ __launch_bounds__(256, 4) void attn_v10(const __hip_bfloat16* __restrict__ h_bT,
                                                   const unsigned* __restrict__ adjw,
                                                   const float* __restrict__ s_i2,
                                                   const float* __restrict__ s_j2,
                                                   __hip_bfloat16* __restrict__ att) {
    __shared__ char smem[36352];
    // staging overlay
    auto hsT = (unsigned short (*)[32][256])smem;           // [2][32][256] bf16 32KB
    auto sjs = (float (*)[256])(smem + 32768);              // [2][256] f32 2KB
    // combine overlay (after final barrier): comb[wv][d(32)][i(69 pad)]
    auto comb  = (float (*)[32][69])smem;                   // 4*32*69*4 = 35328B
    float* combl = (float*)(smem + 35328);                  // [4][64] = 1KB

    const int t = threadIdx.x, lane = t & 63, wv = t >> 6;
    // bijective XCD swizzle: 1024 blocks = 8 XCDs x 128
    const int id = ((int)blockIdx.x & 7) * 128 + ((int)blockIdx.x >> 3);
    const int bh = id >> 4;                   // 16 blocks per bh
    const int b  = bh >> 3, hh = bh & 7;
    const int i0 = (id & 15) * 64;            // block owns i0..i0+63
    const int r16 = lane & 15, jg = lane >> 4;
    const int key = r16 & 7;
    const unsigned shbase = jg * 8;

    float si[4];
    #pragma unroll
    for (int it = 0; it < 4; ++it)
        si[it] = s_i2[(size_t)bh * Nq + i0 + it * 16 + r16];

    const unsigned short* hb = (const unsigned short*)h_bT + (size_t)bh * HDq * Nq;
    const float* sjb = s_j2 + (size_t)bh * Nq;
    // mask base for i-tile 0 row; i-tile offset = it*16*32 = it*512 dwords
    const unsigned* aw0 = adjw + ((size_t)b * Nq + i0 + r16) * 32 + wv * 2;

    auto stage = [&](int nb, int ch) {
        #pragma unroll
        for (int it = 0; it < 4; ++it) {
            int rrb = wv * 8 + it * 2;
            int rr  = rrb + (lane >> 5);
            int oct = (lane & 31) ^ (rr & 7);          // source pre-swizzle
            gload_lds16(hb + (size_t)rr * Nq + ch * 256 + (oct << 3),
                        &hsT[nb][rrb][0]);
        }
        gload_lds16(sjb + ch * 256 + lane * 4, &sjs[nb][0]);  // all waves: uniform vmcnt
    };

    uint2 qm[2][4];
    auto loadmasks = [&](int nb, int ch) {
        #pragma unroll
        for (int it = 0; it < 4; ++it)
            qm[nb][it] = *(const uint2*)(aw0 + ch * 8 + it * 512);
    };

    short8v ones;
    #pragma unroll
    for (int k = 0; k < 8; ++k) ones[k] = (short)0x3F80;

    f32x4 acc[4][2] = {};
    f32x4 accl4[4] = {};

    stage(0, 0);
    loadmasks(0, 0);

    #pragma unroll
    for (int c = 0; c < 4; ++c) {
        const int cb = c & 1;
        if (c < 3) { stage(cb ^ 1, c + 1); loadmasks(cb ^ 1, c + 1); }
        if (c < 3) asm volatile("s_waitcnt vmcnt(9)" ::: "memory");
        else       asm volatile("s_waitcnt vmcnt(0)" ::: "memory");
        __builtin_amdgcn_s_barrier();
        __builtin_amdgcn_sched_barrier(0);

        #pragma unroll
        for (int w = 0; w < 2; ++w) {
            // B-frags for this 32-j window (shared by all 4 i-tiles)
            int oct = (wv * 8 + w * 4 + jg) ^ key;
            short8v fb0 = *(const short8v*)(&hsT[cb][r16][oct << 3]);
            short8v fb1 = *(const short8v*)(&hsT[cb][r16 + 16][oct << 3]);
            f32x4 sv0 = *(const f32x4*)(&sjs[cb][wv * 64 + w * 32 + jg * 8]);
            f32x4 sv1 = *(const f32x4*)(&sjs[cb][wv * 64 + w * 32 + jg * 8 + 4]);
            #pragma unroll
            for (int it = 0; it < 4; ++it) {
                unsigned wbits = (w ? qm[cb][it].y : qm[cb][it].x) >> shbase;
                union { short8v v; __bf16 e[8]; } pa;
                #pragma unroll
                for (int e = 0; e < 8; ++e) {
                    float sc = si[it] + (e < 4 ? sv0[e] : sv1[e - 4]);
                    sc = fmaxf(sc, 0.2f * sc);                 // lrelu (log2)
                    sc = ((wbits >> e) & 1u) ? sc : -30000.f;  // mask -> 0
                    pa.e[e] = (__bf16)__builtin_amdgcn_exp2f(sc);
                }
                acc[it][0] = __builtin_amdgcn_mfma_f32_16x16x32_bf16(pa.v, fb0, acc[it][0], 0, 0, 0);
                acc[it][1] = __builtin_amdgcn_mfma_f32_16x16x32_bf16(pa.v, fb1, acc[it][1], 0, 0, 0);
                accl4[it]  = __builtin_amdgcn_mfma_f32_16x16x32_bf16(pa.v, ones, accl4[it], 0, 0, 0);
            }
        }
        asm volatile("s_waitcnt lgkmcnt(0)" ::: "memory");
        __builtin_amdgcn_s_barrier();          // buf cb consumed by all waves
    }

    // ---- cross-wave combine (staging buffer reused; all reads done) ----
    // lane holds D[row=jg*4+rg][col=r16] for tile it, half h.
    // d-major store: comb[wv][d][i] with i contiguous in rg -> b128 writes.
    #pragma unroll
    for (int it = 0; it < 4; ++it) {
        *(f32x4*)(&comb[wv][r16][it * 16 + jg * 4])      = acc[it][0];
        *(f32x4*)(&comb[wv][r16 + 16][it * 16 + jg * 4]) = acc[it][1];
        if (r16 == 0)
            *(f32x4*)(&combl[wv * 64 + it * 16 + jg * 4]) = accl4[it];
    }
    __syncthreads();

    // final reduce + normalize + bf16 store: thread t -> i = t>>2, 8 d's
    {
        const int i  = t >> 2;
        const int dq = t & 3;
        float l = combl[i] + combl[64 + i] + combl[128 + i] + combl[192 + i];
        float rl = 1.f / l;
        union { short8v v; __hip_bfloat16 e[8]; } ov;
        #pragma unroll
        for (int k = 0; k < 8; ++k) {
            int d = dq * 8 + k;
            float s = comb[0][d][i] + comb[1][d][i] + comb[2][d][i] + comb[3][d][i];
            ov.e[k] = (__hip_bfloat16)(s * rl);
        }
        *(short8v*)((unsigned short*)att + ((size_t)b * Nq + i0 + i) * Dq
                    + hh * HDq + dq * 8) = ov.v;
    }
}

// ---------------------------------------------------------------------------
// Kernel 3: out = LN(att(bf16) + x) * gamma + beta (torch unbiased, /(std+eps))
// ---------------------------------------------------------------------------
__global__ __launch_bounds__(256) void ln_k(const __hip_bfloat16* __restrict__ att,
                                            const float* __restrict__ x,
                                            const float* __restrict__ gamma,
                                            const float* __restrict__ beta,
                                            float* __restrict__ out) {
    const int t = threadIdx.x, lane = t & 63, wv = t >> 6;
    const size_t row  = (size_t)blockIdx.x * 4 + wv;
    const size_t base = row * Dq + lane * 4;
    union { ushort4 u; __hip_bfloat16 e[4]; } av;
    av.u = *(const ushort4*)((const unsigned short*)att + base);
    float4 xv = *(const float4*)(x + base);
    float o0 = (float)av.e[0] + xv.x, o1 = (float)av.e[1] + xv.y;
    float o2 = (float)av.e[2] + xv.z, o3 = (float)av.e[3] + xv.w;
    float s  = o0 + o1 + o2 + o3;
    float sq = o0 * o0 + o1 * o1 + o2 * o2 + o3 * o3;
    #pragma unroll
    for (int off = 32; off; off >>= 1) {
        s  += __shfl_xor(s, off);
        sq += __shfl_xor(sq, off);
    }
    float mean = s * (1.f / 256.f);
    float var  = (sq - 256.f * mean * mean) * (1.f / 255.f);
    var = fmaxf(var, 0.f);
    float inv = 1.f / (sqrtf(var) + 1e-6f);
    float4 g  = *(const float4*)(gamma + lane * 4);
    float4 bt = *(const float4*)(beta + lane * 4);
    float4 ov;
    ov.x = (o0 - mean) * inv * g.x + bt.x;
    ov.y = (o1 - mean) * inv * g.y + bt.y;
    ov.z = (o2 - mean) * inv * g.z + bt.z;
    ov.w = (o3 - mean) * inv * g.w + bt.w;
    *(float4*)(out + base) = ov;
}

// ---------------------------------------------------------------------------
extern "C" void kernel_launch(void* const* d_in, const int* in_sizes, int n_in,
                              void* d_out, int out_size, void* d_ws, size_t ws_size,
                              hipStream_t stream) {
    const float* x     = (const float*)d_in[0];
    const int*   adj   = (const int*)d_in[1];
    const float* W_w   = (const float*)d_in[2];
    const float* W_b   = (const float*)d_in[3];
    const float* a     = (const float*)d_in[4];
    const float* gamma = (const float*)d_in[5];
    const float* beta  = (const float*)d_in[6];
    float* out = (float*)d_out;

    // ws: h_bT [2M bf16 = 4MB] | att [2M bf16 = 4MB] | s_i2 [64K] | s_j2 [64K]
    //     | adjw [256K u32]
    __hip_bfloat16* h_bT = (__hip_bfloat16*)d_ws;
    __hip_bfloat16* att  = (__hip_bfloat16*)((char*)d_ws + (size_t)Bq * Hq * Nq * HDq * 2);
    float* s_i2 = (float*)((char*)att + (size_t)Bq * Nq * Dq * 2);
    float* s_j2 = s_i2 + (size_t)Bq * Hq * Nq;
    unsigned* adjw = (unsigned*)(s_j2 + (size_t)Bq * Hq * Nq);

    gemm_pack<<<2560, 256, 0, stream>>>(x, W_w, W_b, a, adj, h_bT, s_i2, s_j2, adjw);
    attn_v10<<<1024, 256, 0, stream>>>(h_bT, adjw, s_i2, s_j2, att);
    ln_k<<<2048, 256, 0, stream>>>(att, x, gamma, beta, out);
}

// Round 12
// 44.856 us; speedup vs baseline: 1.1183x; 1.1183x over previous
//
#include <hip/hip_runtime.h>
#include <hip/hip_bf16.h>
#include <math.h>

#define Bq 8
#define Nq 1024
#define Dq 256
#define Hq 8
#define HDq 32
#define LOG2E 1.44269504f

typedef __attribute__((ext_vector_type(8)))  short short8v;
typedef __attribute__((ext_vector_type(4)))  float f32x4;
typedef __attribute__((ext_vector_type(16))) float f32x16;

__device__ __forceinline__ void gload_lds16(const void* g, void* l) {
    __builtin_amdgcn_global_load_lds(
        (const __attribute__((address_space(1))) void*)g,
        (__attribute__((address_space(3))) void*)l, 16, 0, 0);
}
__device__ __forceinline__ void gload_lds4(const void* g, void* l) {
    __builtin_amdgcn_global_load_lds(
        (const __attribute__((address_space(1))) void*)g,
        (__attribute__((address_space(3))) void*)l, 4, 0, 0);
}

// ---------------------------------------------------------------------------
// Kernel 1 (fused role-split):
//  blocks [0,512):   bf16 MFMA GEMM h = x*W^T + b, epilogue -> h_bT (bf16,
//                    transposed) + s_i2/s_j2 (prescaled by LOG2E)
//  blocks [512,2560): pack adj rows into bitmasks adjw[b][i][0:32)
// ---------------------------------------------------------------------------
__global__ __launch_bounds__(256) void gemm_pack(const float* __restrict__ x,
                                                 const float* __restrict__ W,
                                                 const float* __restrict__ Wb,
                                                 const float* __restrict__ a,
                                                 const int* __restrict__ adj,
                                                 __hip_bfloat16* __restrict__ h_bT,
                                                 float* __restrict__ s_i2,
                                                 float* __restrict__ s_j2,
                                                 unsigned* __restrict__ adjw) {
    __shared__ __hip_bfloat16 xs[64][68];
    __shared__ __hip_bfloat16 wsm[64][68];
    __shared__ __hip_bfloat16 ht[64][72];
    const int t = threadIdx.x;
    const int lane = t & 63, wv = t >> 6;

    if (blockIdx.x >= 512) {
        const size_t row = ((size_t)blockIdx.x - 512) * 4 + wv;   // 0..8191
        const int* ar = adj + row * Nq;
        unsigned* wr = adjw + row * 32;
        #pragma unroll
        for (int it = 0; it < 16; ++it) {
            int v = ar[it * 64 + lane];
            unsigned long long mask = __ballot(v != 0);
            if (lane == 0) {
                wr[it * 2 + 0] = (unsigned)mask;
                wr[it * 2 + 1] = (unsigned)(mask >> 32);
            }
        }
        return;
    }

    const int m0 = (blockIdx.x & 127) * 64;
    const int o0 = (blockIdx.x >> 7) * 64;
    const int lo = lane & 31, hi = lane >> 5;
    const int mw = (wv & 1) * 32, ow = (wv >> 1) * 32;
    const int b = m0 >> 10;
    f32x16 acc = 0.f;

    for (int k0 = 0; k0 < 256; k0 += 64) {
        __syncthreads();
        #pragma unroll
        for (int it = 0; it < 4; ++it) {
            int f4  = t + it * 256;
            int row = f4 >> 4;
            int c4  = (f4 & 15) * 4;
            float4 xv = *(const float4*)(x + (size_t)(m0 + row) * 256 + k0 + c4);
            float4 wv2 = *(const float4*)(W + (size_t)(o0 + row) * 256 + k0 + c4);
            union { ushort4 u; __bf16 e[4]; } xb, wb;
            xb.e[0] = (__bf16)xv.x; xb.e[1] = (__bf16)xv.y;
            xb.e[2] = (__bf16)xv.z; xb.e[3] = (__bf16)xv.w;
            wb.e[0] = (__bf16)wv2.x; wb.e[1] = (__bf16)wv2.y;
            wb.e[2] = (__bf16)wv2.z; wb.e[3] = (__bf16)wv2.w;
            *(ushort4*)(&xs[row][c4])  = xb.u;
            *(ushort4*)(&wsm[row][c4]) = wb.u;
        }
        __syncthreads();
        #pragma unroll
        for (int kk = 0; kk < 4; ++kk) {
            short8v av = *(const short8v*)(&xs[mw + lo][kk * 16 + hi * 8]);
            short8v bv = *(const short8v*)(&wsm[ow + lo][kk * 16 + hi * 8]);
            acc = __builtin_amdgcn_mfma_f32_32x32x16_bf16(av, bv, acc, 0, 0, 0);
        }
    }

    __syncthreads();
    const float bias = Wb[o0 + ow + lo];
    #pragma unroll
    for (int rg = 0; rg < 16; ++rg) {
        int row = (rg & 3) + 8 * (rg >> 2) + 4 * hi;
        float v = acc[rg] + bias;
        ht[ow + lo][mw + row] = (__hip_bfloat16)v;
    }
    __syncthreads();

    #pragma unroll
    for (int it = 0; it < 2; ++it) {
        int s8 = t + it * 256;
        int ol = s8 >> 3;
        int n8 = (s8 & 7) * 8;
        short8v v = *(const short8v*)(&ht[ol][n8]);
        int o = o0 + ol;
        size_t drow = (size_t)((b * Hq + (o >> 5)) * HDq + (o & 31));
        *(short8v*)((unsigned short*)h_bT + drow * Nq + (m0 & 1023) + n8) = v;
    }
    // s projections: 256 threads, each one 32-dot.
    {
        int which = t >> 7;
        int hd = (t >> 6) & 1, nl = t & 63;
        const float* ab = a + b * 64 + which * 32;
        float s = 0.f;
        #pragma unroll
        for (int d = 0; d < 32; ++d)
            s += (float)ht[hd * 32 + d][nl] * ab[d];
        int bh = b * Hq + (o0 >> 5) + hd;
        int n  = (m0 & 1023) + nl;
        (which ? s_j2 : s_i2)[(size_t)bh * Nq + n] = s * LOG2E;
    }
}

// ---------------------------------------------------------------------------
// Kernel 2: attention v11 — v9 structure at 1.5x occupancy:
// chunks of 128 j (8 chunks), LDS hsT[2][32][128]+sjs[2][128] = 17KB ->
// __launch_bounds__(256,6) = 6 blocks/CU = 24 waves/CU (was 16). Theory:
// v9 was dependency-latency-stalled at 4 waves/SIMD (issue floor ~7us vs
// ~20us measured); more TLP hides the eval->cvt->MFMA and ds_read latency.
// Staging batch: 2 h-gload16 + 2 sj-gload4 + 1 mask uint4 = 5 VMEM/wave,
// counted vmcnt(5). T5 setprio(1) around the compute phase. XOR-swizzled
// conflict-free B-frag reads; native v_exp_f32; l via ones-MFMA.
// ---------------------------------------------------------------------------
__global__ __launch_bounds__(256, 6) void attn_v11(const __hip_bfloat16* __restrict__ h_bT,
                                                   const unsigned* __restrict__ adjw,
                                                   const float* __restrict__ s_i2,
                                                   const float* __restrict__ s_j2,
                                                   __hip_bfloat16* __restrict__ att) {
    __shared__ __hip_bfloat16 hsT[2][32][128];   // 2 x 8KB, linear rows (256B)
    __shared__ float sjs[2][128];                // 2 x 512B
    const int t = threadIdx.x, lane = t & 63, wv = t >> 6;
    // bijective XCD swizzle: 1024 blocks = 8 XCDs x 128
    const int id = ((int)blockIdx.x & 7) * 128 + ((int)blockIdx.x >> 3);
    const int bh = id >> 4;                   // 16 blocks per bh
    const int b  = bh >> 3, hh = bh & 7;
    const int i0 = (id & 15) * 64 + wv * 16;
    const int r16 = lane & 15, jg = lane >> 4;
    const int iG = i0 + r16;
    const int key = r16 & 7;                  // read-side XOR (octet units)
    const unsigned shbase = jg * 8;

    const float si = s_i2[(size_t)bh * Nq + iG];
    const unsigned short* hb = (const unsigned short*)h_bT + (size_t)bh * HDq * Nq;
    const float* sjb = s_j2 + (size_t)bh * Nq;
    const unsigned* awp = adjw + ((size_t)b * Nq + iG) * 32;

    // stage chunk ch (128 j) into buffer nb: 2 h-gload16 (4 rows each) +
    // 2 sj-gload4 (64 floats each). All waves load sjs (same data, benign)
    // so per-wave VMEM count stays uniform for vmcnt bookkeeping.
    auto stage = [&](int nb, int ch) {
        #pragma unroll
        for (int it = 0; it < 2; ++it) {
            int rrb = wv * 8 + it * 4;                 // 4 rows per gload
            int rr  = rrb + (lane >> 4);
            int oct = (lane & 15) ^ (rr & 7);          // source pre-swizzle
            gload_lds16(hb + (size_t)rr * Nq + ch * 128 + (oct << 3),
                        &hsT[nb][rrb][0]);
        }
        gload_lds4(sjb + ch * 128 + lane,      &sjs[nb][0]);
        gload_lds4(sjb + ch * 128 + 64 + lane, &sjs[nb][64]);
    };

    short8v ones;
    #pragma unroll
    for (int k = 0; k < 8; ++k) ones[k] = (short)0x3F80;

    f32x4 acc0 = 0.f, acc1 = 0.f, accl = 0.f;
    uint4 qm[2];

    // prologue: batch 0 (5 VMEM/wave)
    stage(0, 0);
    qm[0] = *(const uint4*)(awp);

    #pragma unroll
    for (int c = 0; c < 8; ++c) {
        const int cb = c & 1;
        if (c < 7) {                           // issue batch c+1 (5 VMEM/wave)
            stage(cb ^ 1, c + 1);
            qm[cb ^ 1] = *(const uint4*)(awp + (c + 1) * 4);
        }
        if (c < 7) asm volatile("s_waitcnt vmcnt(5)" ::: "memory");
        else       asm volatile("s_waitcnt vmcnt(0)" ::: "memory");
        __builtin_amdgcn_s_barrier();          // chunk c data visible to all
        __builtin_amdgcn_sched_barrier(0);
        __builtin_amdgcn_s_setprio(1);

        unsigned aw4[4] = {qm[cb].x, qm[cb].y, qm[cb].z, qm[cb].w};
        const __hip_bfloat16* pr0 = &hsT[cb][r16][0];
        const __hip_bfloat16* pr1 = &hsT[cb][r16 + 16][0];

        #pragma unroll
        for (int w = 0; w < 4; ++w) {
            unsigned wbits = aw4[w] >> shbase;           // word w, bits jg*8+e
            int po = ((w * 4 + jg) ^ key) << 3;          // swizzled octet
            short8v fb0 = *(const short8v*)(pr0 + po);
            short8v fb1 = *(const short8v*)(pr1 + po);
            f32x4 sv0 = *(const f32x4*)(&sjs[cb][w * 32 + jg * 8]);
            f32x4 sv1 = *(const f32x4*)(&sjs[cb][w * 32 + jg * 8 + 4]);
            union { short8v v; __bf16 e[8]; } pa;
            #pragma unroll
            for (int e = 0; e < 8; ++e) {
                float sc = si + (e < 4 ? sv0[e] : sv1[e - 4]);
                sc = fmaxf(sc, 0.2f * sc);                 // lrelu (log2-scaled)
                sc = ((wbits >> e) & 1u) ? sc : -30000.f;  // mask -> exp2 = 0
                pa.e[e] = (__bf16)__builtin_amdgcn_exp2f(sc);
            }
            acc0 = __builtin_amdgcn_mfma_f32_16x16x32_bf16(pa.v, fb0, acc0, 0, 0, 0);
            acc1 = __builtin_amdgcn_mfma_f32_16x16x32_bf16(pa.v, fb1, acc1, 0, 0, 0);
            accl = __builtin_amdgcn_mfma_f32_16x16x32_bf16(pa.v, ones, accl, 0, 0, 0);
        }
        __builtin_amdgcn_s_setprio(0);
        asm volatile("s_waitcnt lgkmcnt(0)" ::: "memory");
        __builtin_amdgcn_s_barrier();          // buf cb free for overwrite
    }

    // epilogue: rows of acc0/acc1/accl align -> no shuffles; bf16 store
    #pragma unroll
    for (int rg = 0; rg < 4; ++rg) {
        int row = jg * 4 + rg;
        float rl = 1.f / accl[rg];
        size_t base = ((size_t)b * Nq + i0 + row) * Dq + hh * HDq;
        att[base + r16]      = (__hip_bfloat16)(acc0[rg] * rl);
        att[base + 16 + r16] = (__hip_bfloat16)(acc1[rg] * rl);
    }
}

// ---------------------------------------------------------------------------
// Kernel 3: out = LN(att(bf16) + x) * gamma + beta (torch unbiased, /(std+eps))
// ---------------------------------------------------------------------------
__global__ __launch_bounds__(256) void ln_k(const __hip_bfloat16* __restrict__ att,
                                            const float* __restrict__ x,
                                            const float* __restrict__ gamma,
                                            const float* __restrict__ beta,
                                            float* __restrict__ out) {
    const int t = threadIdx.x, lane = t & 63, wv = t >> 6;
    const size_t row  = (size_t)blockIdx.x * 4 + wv;
    const size_t base = row * Dq + lane * 4;
    union { ushort4 u; __hip_bfloat16 e[4]; } av;
    av.u = *(const ushort4*)((const unsigned short*)att + base);
    float4 xv = *(const float4*)(x + base);
    float o0 = (float)av.e[0] + xv.x, o1 = (float)av.e[1] + xv.y;
    float o2 = (float)av.e[2] + xv.z, o3 = (float)av.e[3] + xv.w;
    float s  = o0 + o1 + o2 + o3;
    float sq = o0 * o0 + o1 * o1 + o2 * o2 + o3 * o3;
    #pragma unroll
    for (int off = 32; off; off >>= 1) {
        s  += __shfl_xor(s, off);
        sq += __shfl_xor(sq, off);
    }
    float mean = s * (1.f / 256.f);
    float var  = (sq - 256.f * mean * mean) * (1.f / 255.f);
    var = fmaxf(var, 0.f);
    float inv = 1.f / (sqrtf(var) + 1e-6f);
    float4 g  = *(const float4*)(gamma + lane * 4);
    float4 bt = *(const float4*)(beta + lane * 4);
    float4 ov;
    ov.x = (o0 - mean) * inv * g.x + bt.x;
    ov.y = (o1 - mean) * inv * g.y + bt.y;
    ov.z = (o2 - mean) * inv * g.z + bt.z;
    ov.w = (o3 - mean) * inv * g.w + bt.w;
    *(float4*)(out + base) = ov;
}

// ---------------------------------------------------------------------------
extern "C" void kernel_launch(void* const* d_in, const int* in_sizes, int n_in,
                              void* d_out, int out_size, void* d_ws, size_t ws_size,
                              hipStream_t stream) {
    const float* x     = (const float*)d_in[0];
    const int*   adj   = (const int*)d_in[1];
    const float* W_w   = (const float*)d_in[2];
    const float* W_b   = (const float*)d_in[3];
    const float* a     = (const float*)d_in[4];
    const float* gamma = (const float*)d_in[5];
    const float* beta  = (const float*)d_in[6];
    float* out = (float*)d_out;

    // ws: h_bT [2M bf16 = 4MB] | att [2M bf16 = 4MB] | s_i2 [64K] | s_j2 [64K]
    //     | adjw [256K u32]
    __hip_bfloat16* h_bT = (__hip_bfloat16*)d_ws;
    __hip_bfloat16* att  = (__hip_bfloat16*)((char*)d_ws + (size_t)Bq * Hq * Nq * HDq * 2);
    float* s_i2 = (float*)((char*)att + (size_t)Bq * Nq * Dq * 2);
    float* s_j2 = s_i2 + (size_t)Bq * Hq * Nq;
    unsigned* adjw = (unsigned*)(s_j2 + (size_t)Bq * Hq * Nq);

    gemm_pack<<<2560, 256, 0, stream>>>(x, W_w, W_b, a, adj, h_bT, s_i2, s_j2, adjw);
    attn_v11<<<1024, 256, 0, stream>>>(h_bT, adjw, s_i2, s_j2, att);
    ln_k<<<2048, 256, 0, stream>>>(att, x, gamma, beta, out);
}

// Round 13
// 42.375 us; speedup vs baseline: 1.1837x; 1.0585x over previous
//
#include <hip/hip_runtime.h>
#include <hip/hip_bf16.h>
#include <math.h>

#define Bq 8
#define Nq 1024
#define Dq 256
#define Hq 8
#define HDq 32
#define LOG2E 1.44269504f

typedef __attribute__((ext_vector_type(8)))  short short8v;
typedef __attribute__((ext_vector_type(2)))  float f32x2;
typedef __attribute__((ext_vector_type(4)))  float f32x4;
typedef __attribute__((ext_vector_type(16))) float f32x16;

__device__ __forceinline__ void gload_lds16(const void* g, void* l) {
    __builtin_amdgcn_global_load_lds(
        (const __attribute__((address_space(1))) void*)g,
        (__attribute__((address_space(3))) void*)l, 16, 0, 0);
}
__device__ __forceinline__ void gload_lds4(const void* g, void* l) {
    __builtin_amdgcn_global_load_lds(
        (const __attribute__((address_space(1))) void*)g,
        (__attribute__((address_space(3))) void*)l, 4, 0, 0);
}
__device__ __forceinline__ unsigned cvtpk_bf16(float lo, float hi) {
    unsigned r;
    asm("v_cvt_pk_bf16_f32 %0, %1, %2" : "=v"(r) : "v"(lo), "v"(hi));
    return r;
}

// ---------------------------------------------------------------------------
// Kernel 1 (fused role-split):
//  blocks [0,512):   bf16 MFMA GEMM h = x*W^T + b, epilogue -> h_bT (bf16,
//                    transposed) + s_i2/s_j2 (prescaled by LOG2E)
//  blocks [512,2560): pack adj rows into bitmasks adjw[b][i][0:32)
// ---------------------------------------------------------------------------
__global__ __launch_bounds__(256) void gemm_pack(const float* __restrict__ x,
                                                 const float* __restrict__ W,
                                                 const float* __restrict__ Wb,
                                                 const float* __restrict__ a,
                                                 const int* __restrict__ adj,
                                                 __hip_bfloat16* __restrict__ h_bT,
                                                 float* __restrict__ s_i2,
                                                 float* __restrict__ s_j2,
                                                 unsigned* __restrict__ adjw) {
    __shared__ __hip_bfloat16 xs[64][68];
    __shared__ __hip_bfloat16 wsm[64][68];
    __shared__ __hip_bfloat16 ht[64][72];
    const int t = threadIdx.x;
    const int lane = t & 63, wv = t >> 6;

    if (blockIdx.x >= 512) {
        const size_t row = ((size_t)blockIdx.x - 512) * 4 + wv;   // 0..8191
        const int* ar = adj + row * Nq;
        unsigned* wr = adjw + row * 32;
        #pragma unroll
        for (int it = 0; it < 16; ++it) {
            int v = ar[it * 64 + lane];
            unsigned long long mask = __ballot(v != 0);
            if (lane == 0) {
                wr[it * 2 + 0] = (unsigned)mask;
                wr[it * 2 + 1] = (unsigned)(mask >> 32);
            }
        }
        return;
    }

    const int m0 = (blockIdx.x & 127) * 64;
    const int o0 = (blockIdx.x >> 7) * 64;
    const int lo = lane & 31, hi = lane >> 5;
    const int mw = (wv & 1) * 32, ow = (wv >> 1) * 32;
    const int b = m0 >> 10;
    f32x16 acc = 0.f;

    for (int k0 = 0; k0 < 256; k0 += 64) {
        __syncthreads();
        #pragma unroll
        for (int it = 0; it < 4; ++it) {
            int f4  = t + it * 256;
            int row = f4 >> 4;
            int c4  = (f4 & 15) * 4;
            float4 xv = *(const float4*)(x + (size_t)(m0 + row) * 256 + k0 + c4);
            float4 wv2 = *(const float4*)(W + (size_t)(o0 + row) * 256 + k0 + c4);
            union { ushort4 u; __bf16 e[4]; } xb, wb;
            xb.e[0] = (__bf16)xv.x; xb.e[1] = (__bf16)xv.y;
            xb.e[2] = (__bf16)xv.z; xb.e[3] = (__bf16)xv.w;
            wb.e[0] = (__bf16)wv2.x; wb.e[1] = (__bf16)wv2.y;
            wb.e[2] = (__bf16)wv2.z; wb.e[3] = (__bf16)wv2.w;
            *(ushort4*)(&xs[row][c4])  = xb.u;
            *(ushort4*)(&wsm[row][c4]) = wb.u;
        }
        __syncthreads();
        #pragma unroll
        for (int kk = 0; kk < 4; ++kk) {
            short8v av = *(const short8v*)(&xs[mw + lo][kk * 16 + hi * 8]);
            short8v bv = *(const short8v*)(&wsm[ow + lo][kk * 16 + hi * 8]);
            acc = __builtin_amdgcn_mfma_f32_32x32x16_bf16(av, bv, acc, 0, 0, 0);
        }
    }

    __syncthreads();
    const float bias = Wb[o0 + ow + lo];
    #pragma unroll
    for (int rg = 0; rg < 16; ++rg) {
        int row = (rg & 3) + 8 * (rg >> 2) + 4 * hi;
        float v = acc[rg] + bias;
        ht[ow + lo][mw + row] = (__hip_bfloat16)v;
    }
    __syncthreads();

    #pragma unroll
    for (int it = 0; it < 2; ++it) {
        int s8 = t + it * 256;
        int ol = s8 >> 3;
        int n8 = (s8 & 7) * 8;
        short8v v = *(const short8v*)(&ht[ol][n8]);
        int o = o0 + ol;
        size_t drow = (size_t)((b * Hq + (o >> 5)) * HDq + (o & 31));
        *(short8v*)((unsigned short*)h_bT + drow * Nq + (m0 & 1023) + n8) = v;
    }
    // s projections: 256 threads, each one 32-dot.
    {
        int which = t >> 7;
        int hd = (t >> 6) & 1, nl = t & 63;
        const float* ab = a + b * 64 + which * 32;
        float s = 0.f;
        #pragma unroll
        for (int d = 0; d < 32; ++d)
            s += (float)ht[hd * 32 + d][nl] * ab[d];
        int bh = b * Hq + (o0 >> 5) + hd;
        int n  = (m0 & 1023) + nl;
        (which ? s_j2 : s_i2)[(size_t)bh * Nq + n] = s * LOG2E;
    }
}

// ---------------------------------------------------------------------------
// Kernel 2: attention v12 — v11 structure (17KB dbuf staging, counted
// vmcnt(5), 6 blocks/CU, XOR-swizzled B-frags) with a slimmed window eval:
//  * v_cvt_pk_bf16_f32 inline asm: 4 inst replace ~28 (no scalar bf16 cvt
//    on gfx950; the (__bf16) cast was emitting a multi-inst RTNE sequence)
//  * mask applied post-exp by ANDing packed bf16 with a 4KB LDS LUT entry
//    (lut[byte] = 4 u32 of half-masks): 1 ds_read_b128 + 4 v_and replace
//    24 shift/and/cndmask. Exact: unmasked p <= 2^36 finite; AND -> +0.0.
//  * score math on f32x2 (chance of v_pk_add/mul/max dual-issue)
// ---------------------------------------------------------------------------
__global__ __launch_bounds__(256, 6) void attn_v12(const __hip_bfloat16* __restrict__ h_bT,
                                                   const unsigned* __restrict__ adjw,
                                                   const float* __restrict__ s_i2,
                                                   const float* __restrict__ s_j2,
                                                   __hip_bfloat16* __restrict__ att) {
    __shared__ __hip_bfloat16 hsT[2][32][128];   // 2 x 8KB, linear rows (256B)
    __shared__ float sjs[2][128];                // 2 x 512B
    __shared__ uint4 lut[256];                   // 4KB mask LUT
    const int t = threadIdx.x, lane = t & 63, wv = t >> 6;
    // bijective XCD swizzle: 1024 blocks = 8 XCDs x 128
    const int id = ((int)blockIdx.x & 7) * 128 + ((int)blockIdx.x >> 3);
    const int bh = id >> 4;                   // 16 blocks per bh
    const int b  = bh >> 3, hh = bh & 7;
    const int i0 = (id & 15) * 64 + wv * 16;
    const int r16 = lane & 15, jg = lane >> 4;
    const int iG = i0 + r16;
    const int key = r16 & 7;                  // read-side XOR (octet units)
    const unsigned shbase = jg * 8;

    // build mask LUT: entry[byte] = 8 bf16 half-masks (bit e -> 0xFFFF/0)
    {
        unsigned bv = t;
        unsigned w0 = ((bv & 1u)  ? 0xFFFFu : 0u) | ((bv & 2u)   ? 0xFFFF0000u : 0u);
        unsigned w1 = ((bv & 4u)  ? 0xFFFFu : 0u) | ((bv & 8u)   ? 0xFFFF0000u : 0u);
        unsigned w2 = ((bv & 16u) ? 0xFFFFu : 0u) | ((bv & 32u)  ? 0xFFFF0000u : 0u);
        unsigned w3 = ((bv & 64u) ? 0xFFFFu : 0u) | ((bv & 128u) ? 0xFFFF0000u : 0u);
        lut[t] = (uint4){w0, w1, w2, w3};
    }
    __syncthreads();

    const float si = s_i2[(size_t)bh * Nq + iG];
    const f32x2 si2 = {si, si};
    const unsigned short* hb = (const unsigned short*)h_bT + (size_t)bh * HDq * Nq;
    const float* sjb = s_j2 + (size_t)bh * Nq;
    const unsigned* awp = adjw + ((size_t)b * Nq + iG) * 32;

    auto stage = [&](int nb, int ch) {
        #pragma unroll
        for (int it = 0; it < 2; ++it) {
            int rrb = wv * 8 + it * 4;                 // 4 rows per gload
            int rr  = rrb + (lane >> 4);
            int oct = (lane & 15) ^ (rr & 7);          // source pre-swizzle
            gload_lds16(hb + (size_t)rr * Nq + ch * 128 + (oct << 3),
                        &hsT[nb][rrb][0]);
        }
        gload_lds4(sjb + ch * 128 + lane,      &sjs[nb][0]);
        gload_lds4(sjb + ch * 128 + 64 + lane, &sjs[nb][64]);
    };

    short8v ones;
    #pragma unroll
    for (int k = 0; k < 8; ++k) ones[k] = (short)0x3F80;

    f32x4 acc0 = 0.f, acc1 = 0.f, accl = 0.f;
    uint4 qm[2];

    // prologue: batch 0 (5 VMEM/wave)
    stage(0, 0);
    qm[0] = *(const uint4*)(awp);

    #pragma unroll
    for (int c = 0; c < 8; ++c) {
        const int cb = c & 1;
        if (c < 7) {                           // issue batch c+1 (5 VMEM/wave)
            stage(cb ^ 1, c + 1);
            qm[cb ^ 1] = *(const uint4*)(awp + (c + 1) * 4);
        }
        if (c < 7) asm volatile("s_waitcnt vmcnt(5)" ::: "memory");
        else       asm volatile("s_waitcnt vmcnt(0)" ::: "memory");
        __builtin_amdgcn_s_barrier();          // chunk c data visible to all
        __builtin_amdgcn_sched_barrier(0);
        __builtin_amdgcn_s_setprio(1);

        unsigned aw4[4] = {qm[cb].x, qm[cb].y, qm[cb].z, qm[cb].w};
        const __hip_bfloat16* pr0 = &hsT[cb][r16][0];
        const __hip_bfloat16* pr1 = &hsT[cb][r16 + 16][0];

        #pragma unroll
        for (int w = 0; w < 4; ++w) {
            uint4 mk = lut[(aw4[w] >> shbase) & 0xFFu]; // 8 half-masks
            int po = ((w * 4 + jg) ^ key) << 3;          // swizzled octet
            short8v fb0 = *(const short8v*)(pr0 + po);
            short8v fb1 = *(const short8v*)(pr1 + po);
            f32x4 sv0 = *(const f32x4*)(&sjs[cb][w * 32 + jg * 8]);
            f32x4 sv1 = *(const f32x4*)(&sjs[cb][w * 32 + jg * 8 + 4]);
            f32x2 a0 = si2 + (f32x2){sv0[0], sv0[1]};
            f32x2 a1 = si2 + (f32x2){sv0[2], sv0[3]};
            f32x2 a2 = si2 + (f32x2){sv1[0], sv1[1]};
            f32x2 a3 = si2 + (f32x2){sv1[2], sv1[3]};
            a0 = __builtin_elementwise_max(a0, a0 * 0.2f);   // lrelu (log2)
            a1 = __builtin_elementwise_max(a1, a1 * 0.2f);
            a2 = __builtin_elementwise_max(a2, a2 * 0.2f);
            a3 = __builtin_elementwise_max(a3, a3 * 0.2f);
            union { short8v v; unsigned u[4]; } pa;
            pa.u[0] = cvtpk_bf16(__builtin_amdgcn_exp2f(a0.x),
                                 __builtin_amdgcn_exp2f(a0.y)) & mk.x;
            pa.u[1] = cvtpk_bf16(__builtin_amdgcn_exp2f(a1.x),
                                 __builtin_amdgcn_exp2f(a1.y)) & mk.y;
            pa.u[2] = cvtpk_bf16(__builtin_amdgcn_exp2f(a2.x),
                                 __builtin_amdgcn_exp2f(a2.y)) & mk.z;
            pa.u[3] = cvtpk_bf16(__builtin_amdgcn_exp2f(a3.x),
                                 __builtin_amdgcn_exp2f(a3.y)) & mk.w;
            acc0 = __builtin_amdgcn_mfma_f32_16x16x32_bf16(pa.v, fb0, acc0, 0, 0, 0);
            acc1 = __builtin_amdgcn_mfma_f32_16x16x32_bf16(pa.v, fb1, acc1, 0, 0, 0);
            accl = __builtin_amdgcn_mfma_f32_16x16x32_bf16(pa.v, ones, accl, 0, 0, 0);
        }
        __builtin_amdgcn_s_setprio(0);
        asm volatile("s_waitcnt lgkmcnt(0)" ::: "memory");
        __builtin_amdgcn_s_barrier();          // buf cb free for overwrite
    }

    // epilogue: rows of acc0/acc1/accl align -> no shuffles; bf16 store
    #pragma unroll
    for (int rg = 0; rg < 4; ++rg) {
        int row = jg * 4 + rg;
        float rl = 1.f / accl[rg];
        size_t base = ((size_t)b * Nq + i0 + row) * Dq + hh * HDq;
        att[base + r16]      = (__hip_bfloat16)(acc0[rg] * rl);
        att[base + 16 + r16] = (__hip_bfloat16)(acc1[rg] * rl);
    }
}

// ---------------------------------------------------------------------------
// Kernel 3: out = LN(att(bf16) + x) * gamma + beta (torch unbiased, /(std+eps))
// ---------------------------------------------------------------------------
__global__ __launch_bounds__(256) void ln_k(const __hip_bfloat16* __restrict__ att,
                                            const float* __restrict__ x,
                                            const float* __restrict__ gamma,
                                            const float* __restrict__ beta,
                                            float* __restrict__ out) {
    const int t = threadIdx.x, lane = t & 63, wv = t >> 6;
    const size_t row  = (size_t)blockIdx.x * 4 + wv;
    const size_t base = row * Dq + lane * 4;
    union { ushort4 u; __hip_bfloat16 e[4]; } av;
    av.u = *(const ushort4*)((const unsigned short*)att + base);
    float4 xv = *(const float4*)(x + base);
    float o0 = (float)av.e[0] + xv.x, o1 = (float)av.e[1] + xv.y;
    float o2 = (float)av.e[2] + xv.z, o3 = (float)av.e[3] + xv.w;
    float s  = o0 + o1 + o2 + o3;
    float sq = o0 * o0 + o1 * o1 + o2 * o2 + o3 * o3;
    #pragma unroll
    for (int off = 32; off; off >>= 1) {
        s  += __shfl_xor(s, off);
        sq += __shfl_xor(sq, off);
    }
    float mean = s * (1.f / 256.f);
    float var  = (sq - 256.f * mean * mean) * (1.f / 255.f);
    var = fmaxf(var, 0.f);
    float inv = 1.f / (sqrtf(var) + 1e-6f);
    float4 g  = *(const float4*)(gamma + lane * 4);
    float4 bt = *(const float4*)(beta + lane * 4);
    float4 ov;
    ov.x = (o0 - mean) * inv * g.x + bt.x;
    ov.y = (o1 - mean) * inv * g.y + bt.y;
    ov.z = (o2 - mean) * inv * g.z + bt.z;
    ov.w = (o3 - mean) * inv * g.w + bt.w;
    *(float4*)(out + base) = ov;
}

// ---------------------------------------------------------------------------
extern "C" void kernel_launch(void* const* d_in, const int* in_sizes, int n_in,
                              void* d_out, int out_size, void* d_ws, size_t ws_size,
                              hipStream_t stream) {
    const float* x     = (const float*)d_in[0];
    const int*   adj   = (const int*)d_in[1];
    const float* W_w   = (const float*)d_in[2];
    const float* W_b   = (const float*)d_in[3];
    const float* a     = (const float*)d_in[4];
    const float* gamma = (const float*)d_in[5];
    const float* beta  = (const float*)d_in[6];
    float* out = (float*)d_out;

    // ws: h_bT [2M bf16 = 4MB] | att [2M bf16 = 4MB] | s_i2 [64K] | s_j2 [64K]
    //     | adjw [256K u32]
    __hip_bfloat16* h_bT = (__hip_bfloat16*)d_ws;
    __hip_bfloat16* att  = (__hip_bfloat16*)((char*)d_ws + (size_t)Bq * Hq * Nq * HDq * 2);
    float* s_i2 = (float*)((char*)att + (size_t)Bq * Nq * Dq * 2);
    float* s_j2 = s_i2 + (size_t)Bq * Hq * Nq;
    unsigned* adjw = (unsigned*)(s_j2 + (size_t)Bq * Hq * Nq);

    gemm_pack<<<2560, 256, 0, stream>>>(x, W_w, W_b, a, adj, h_bT, s_i2, s_j2, adjw);
    attn_v12<<<1024, 256, 0, stream>>>(h_bT, adjw, s_i2, s_j2, att);
    ln_k<<<2048, 256, 0, stream>>>(att, x, gamma, beta, out);
}